// Round 3
// baseline (307.077 us; speedup 1.0000x reference)
//
#include <hip/hip_runtime.h>

// KMeans assignment: costs[i] = min_k ||x_i-c_k||^2, indices[i] = argmin_k.
// argmin over k of (c2[k] - 2*dot(x,c_k)); x2 additive, added at the end.
// Cross term via split-f16 3-pass MFMA (xh.ch + xl.ch + xh.cl), err ~1e-5.
// R3 restructure: B fragments read DIRECTLY global->registers from the
// pre-tiled L2-resident layout (512 KB) -- no per-chunk LDS staging, no
// barriers in the K-loop, fine-grained vmcnt pipelining by the compiler.
// N=131072, D=128, K=1024.  d_out = [costs (N f32), indices-as-f32 (N)].

typedef _Float16 f16x8 __attribute__((ext_vector_type(8)));
typedef float    f32x4 __attribute__((ext_vector_type(4)));
typedef unsigned short u16;

constexpr int N = 131072, D = 128, K = 1024;
constexpr int MT = 128;   // points per block

union H2U { _Float16 h; unsigned short u; };

// ---- prep: centers -> hi/lo f16 in fragment-major tiled layout + exact c2 ----
// ushort idx: (((cb*4 + kc)*4 + q)*128 + c%128)*8 + j, k = kc*32 + q*8 + j
__global__ void prep_centers(const float* __restrict__ centers,
                             u16* __restrict__ Bh, u16* __restrict__ Bl,
                             float* __restrict__ c2) {
  const int wave = threadIdx.x >> 6, lane = threadIdx.x & 63;
  const int c = blockIdx.x * 4 + wave;          // one wave per center
  const float2 v = ((const float2*)(centers + (size_t)c * D))[lane];
  float s = v.x * v.x + v.y * v.y;
  #pragma unroll
  for (int off = 32; off; off >>= 1) s += __shfl_xor(s, off, 64);
  if (lane == 0) c2[c] = s;

  H2U h0, h1, l0, l1;
  h0.h = (_Float16)v.x;  l0.h = (_Float16)(v.x - (float)h0.h);
  h1.h = (_Float16)v.y;  l1.h = (_Float16)(v.y - (float)h1.h);
  const int cb = c >> 7, cm = c & 127;
  const int kc = lane >> 4, q = (lane >> 2) & 3, j0 = (lane & 3) * 2;
  const size_t off = (((size_t)(cb * 4 + kc) * 4 + q) * 128 + cm) * 8 + j0;
  *(unsigned*)(Bh + off) = (unsigned)h0.u | ((unsigned)h1.u << 16);
  *(unsigned*)(Bl + off) = (unsigned)l0.u | ((unsigned)l1.u << 16);
}

// ---- main: 128 pts x 1024 centers per block; wave tile 64x64 (2x2 waves) ----
__global__ __launch_bounds__(256, 2) void kmeans_mfma(
    const float* __restrict__ x,
    const u16* __restrict__ Bh_g, const u16* __restrict__ Bl_g,
    const float* __restrict__ c2g,
    float* __restrict__ out_cost, float* __restrict__ out_idx)
{
  // 70 KB -> 2 blocks/CU
  __shared__ __align__(16) u16 Ah[16384];   // [kc4][q4][m128][j8]  32 KB
  __shared__ __align__(16) u16 Al[16384];   //                      32 KB
  __shared__ float c2l[K];                  //                       4 KB
  __shared__ float redV[256];               //                       1 KB
  __shared__ int   redI[256];               //                       1 KB

  const int tid = threadIdx.x;
  const int wave = tid >> 6, lane = tid & 63;
  const int wr = wave >> 1, wc = wave & 1;    // wave row/col in 2x2
  const int q = lane >> 4, ln = lane & 15;
  const int m0 = blockIdx.x * MT;

  // ---- stage A tile: fp32 -> (hi,lo) f16, tiled layout, once per block ----
  #pragma unroll
  for (int i = 0; i < 16; ++i) {
    const int flat = i * 256 + tid;            // 4096 float4s = 128x128 floats
    const int m = flat >> 5, c4 = flat & 31, k0 = c4 * 4;
    const float4 v = *(const float4*)(x + (size_t)(m0 + m) * D + k0);
    const int kc = k0 >> 5, qq = (k0 >> 3) & 3, j0 = k0 & 7;
    const float vv[4] = {v.x, v.y, v.z, v.w};
    H2U h[4], l[4];
    #pragma unroll
    for (int z = 0; z < 4; ++z) {
      h[z].h = (_Float16)vv[z];
      l[z].h = (_Float16)(vv[z] - (float)h[z].h);
    }
    const int off = ((kc * 4 + qq) * 128 + m) * 8 + j0;
    uint2 hp, lp;
    hp.x = h[0].u | ((unsigned)h[1].u << 16); hp.y = h[2].u | ((unsigned)h[3].u << 16);
    lp.x = l[0].u | ((unsigned)l[1].u << 16); lp.y = l[2].u | ((unsigned)l[3].u << 16);
    *(uint2*)(Ah + off) = hp;
    *(uint2*)(Al + off) = lp;
  }
  for (int i = tid; i < K; i += 256) c2l[i] = c2g[i];
  __syncthreads();

  // ---- x2 per point (thread tid<128 owns m=tid) ----
  float x2m = 0.f;
  if (tid < MT) {
    #pragma unroll
    for (int kq = 0; kq < 16; ++kq) {
      const f16x8 hv = *(const f16x8*)(Ah + (kq * 128 + tid) * 8);
      const f16x8 lv = *(const f16x8*)(Al + (kq * 128 + tid) * 8);
      #pragma unroll
      for (int e = 0; e < 8; ++e) {
        const float xv = (float)hv[e] + (float)lv[e];
        x2m += xv * xv;
      }
    }
  }

  float bestV[16]; int bestI[16];
  #pragma unroll
  for (int b = 0; b < 16; ++b) { bestV[b] = 3.4e38f; bestI[b] = 0; }

  for (int ct = 0; ct < 8; ++ct) {
    f32x4 acc[4][4];
    #pragma unroll
    for (int mt = 0; mt < 4; ++mt)
      #pragma unroll
      for (int nt = 0; nt < 4; ++nt)
        acc[mt][nt] = (f32x4){0.f, 0.f, 0.f, 0.f};

    #pragma unroll
    for (int kc = 0; kc < 4; ++kc) {
      // B frags straight from global (L2-resident, fragment-major layout);
      // no barrier, compiler pipelines with fine-grained vmcnt.
      f16x8 ah[4], al[4], bh[4], bl[4];
      #pragma unroll
      for (int t = 0; t < 4; ++t) {
        const size_t noff =
            ((size_t)((ct * 4 + kc) * 4 + q) * 128 + wc * 64 + t * 16 + ln) * 8;
        bh[t] = *(const f16x8*)(Bh_g + noff);
        bl[t] = *(const f16x8*)(Bl_g + noff);
        const int moff = ((kc * 4 + q) * 128 + wr * 64 + t * 16 + ln) * 8;
        ah[t] = *(const f16x8*)(Ah + moff);
        al[t] = *(const f16x8*)(Al + moff);
      }
      // 3-pass split-f16: 48 MFMA per chunk
      #pragma unroll
      for (int mt = 0; mt < 4; ++mt)
        #pragma unroll
        for (int nt = 0; nt < 4; ++nt)
          acc[mt][nt] = __builtin_amdgcn_mfma_f32_16x16x32_f16(ah[mt], bh[nt], acc[mt][nt], 0, 0, 0);
      #pragma unroll
      for (int mt = 0; mt < 4; ++mt)
        #pragma unroll
        for (int nt = 0; nt < 4; ++nt)
          acc[mt][nt] = __builtin_amdgcn_mfma_f32_16x16x32_f16(al[mt], bh[nt], acc[mt][nt], 0, 0, 0);
      #pragma unroll
      for (int mt = 0; mt < 4; ++mt)
        #pragma unroll
        for (int nt = 0; nt < 4; ++nt)
          acc[mt][nt] = __builtin_amdgcn_mfma_f32_16x16x32_f16(ah[mt], bl[nt], acc[mt][nt], 0, 0, 0);
    }

    // epilogue: s = c2 - 2*dot; running min (n strictly increasing per lane)
    #pragma unroll
    for (int nt = 0; nt < 4; ++nt) {
      const int n = ct * 128 + wc * 64 + nt * 16 + ln;
      const float c2v = c2l[n];
      #pragma unroll
      for (int mt = 0; mt < 4; ++mt)
        #pragma unroll
        for (int r = 0; r < 4; ++r) {
          const float s = __builtin_fmaf(-2.f, acc[mt][nt][r], c2v);
          const int b = mt * 4 + r;
          if (s < bestV[b]) { bestV[b] = s; bestI[b] = n; }
        }
    }
  }

  // ---- reduce across the 16 lanes (ln) sharing the same m rows ----
  #pragma unroll
  for (int b = 0; b < 16; ++b) {
    float v = bestV[b]; int idx = bestI[b];
    #pragma unroll
    for (int off = 1; off < 16; off <<= 1) {
      const float ov = __shfl_xor(v, off, 64);
      const int   oi = __shfl_xor(idx, off, 64);
      if (ov < v || (ov == v && oi < idx)) { v = ov; idx = oi; }
    }
    bestV[b] = v; bestI[b] = idx;
  }

  if (ln == 0) {
    #pragma unroll
    for (int b = 0; b < 16; ++b) {
      const int ml = wr * 64 + (b >> 2) * 16 + q * 4 + (b & 3);
      redV[ml * 2 + wc] = bestV[b];
      redI[ml * 2 + wc] = bestI[b];
    }
  }
  __syncthreads();
  if (tid < MT) {
    float v = redV[tid * 2]; int idx = redI[tid * 2];
    const float v1 = redV[tid * 2 + 1]; const int i1 = redI[tid * 2 + 1];
    if (v1 < v || (v1 == v && i1 < idx)) { v = v1; idx = i1; }
    float cost = x2m + v;
    if (cost < 0.f) cost = 0.f;          // clamp like reference
    out_cost[m0 + tid] = cost;
    out_idx[m0 + tid]  = (float)idx;
  }
}

extern "C" void kernel_launch(void* const* d_in, const int* in_sizes, int n_in,
                              void* d_out, int out_size, void* d_ws, size_t ws_size,
                              hipStream_t stream) {
  const float* x       = (const float*)d_in[0];
  const float* centers = (const float*)d_in[1];
  u16*   Bh = (u16*)d_ws;                    // 256 KB
  u16*   Bl = Bh + (size_t)K * D;            // 256 KB
  float* c2 = (float*)(Bl + (size_t)K * D);  // 4 KB
  float* out_cost = (float*)d_out;
  float* out_idx  = out_cost + N;

  prep_centers<<<K / 4, 256, 0, stream>>>(centers, Bh, Bl, c2);
  kmeans_mfma<<<N / MT, 256, 0, stream>>>(x, Bh, Bl, c2, out_cost, out_idx);
}

// Round 4
// 199.727 us; speedup vs baseline: 1.5375x; 1.5375x over previous
//
#include <hip/hip_runtime.h>

// KMeans assignment: costs[i] = min_k ||x_i-c_k||^2, indices[i] = argmin_k.
// argmin over k of (c2[k] - 2*dot(x,c_k)); x2 additive, added at the end.
// Cross term via split-f16 3-pass MFMA (xh.ch + xl.ch + xh.cl), err ~1e-5.
// R4: A panel held in REGISTERS (128 VGPR/lane, loaded once) -> per-chunk LDS
// reads halve; B staged via global_load_lds into a DOUBLE-BUFFER overlaid on
// the freed A LDS region; one barrier per chunk, prefetch issued a full
// chunk-compute ahead so the pre-barrier vmcnt(0) drain is ~free.
// N=131072, D=128, K=1024.  d_out = [costs (N f32), indices-as-f32 (N)].

typedef _Float16 f16x8 __attribute__((ext_vector_type(8)));
typedef float    f32x4 __attribute__((ext_vector_type(4)));
typedef unsigned short u16;

constexpr int N = 131072, D = 128, K = 1024;
constexpr int MT = 128;   // points per block

union H2U { _Float16 h; unsigned short u; };

__device__ inline void gl_lds16(const void* g, void* l) {
  __builtin_amdgcn_global_load_lds(
      (const __attribute__((address_space(1))) unsigned int*)g,
      (__attribute__((address_space(3))) unsigned int*)l, 16, 0, 0);
}

// ---- prep: centers -> hi/lo f16 in fragment-major tiled layout + exact c2 ----
// ushort idx: (((cb*4 + kc)*4 + q)*128 + c%128)*8 + j, k = kc*32 + q*8 + j
__global__ void prep_centers(const float* __restrict__ centers,
                             u16* __restrict__ Bh, u16* __restrict__ Bl,
                             float* __restrict__ c2) {
  const int wave = threadIdx.x >> 6, lane = threadIdx.x & 63;
  const int c = blockIdx.x * 4 + wave;          // one wave per center
  const float2 v = ((const float2*)(centers + (size_t)c * D))[lane];
  float s = v.x * v.x + v.y * v.y;
  #pragma unroll
  for (int off = 32; off; off >>= 1) s += __shfl_xor(s, off, 64);
  if (lane == 0) c2[c] = s;

  H2U h0, h1, l0, l1;
  h0.h = (_Float16)v.x;  l0.h = (_Float16)(v.x - (float)h0.h);
  h1.h = (_Float16)v.y;  l1.h = (_Float16)(v.y - (float)h1.h);
  const int cb = c >> 7, cm = c & 127;
  const int kc = lane >> 4, q = (lane >> 2) & 3, j0 = (lane & 3) * 2;
  const size_t off = (((size_t)(cb * 4 + kc) * 4 + q) * 128 + cm) * 8 + j0;
  *(unsigned*)(Bh + off) = (unsigned)h0.u | ((unsigned)h1.u << 16);
  *(unsigned*)(Bl + off) = (unsigned)l0.u | ((unsigned)l1.u << 16);
}

// ---- main: 128 pts x 1024 centers per block; wave tile 64x64 (2x2 waves) ----
__global__ __launch_bounds__(256, 2) void kmeans_mfma(
    const float* __restrict__ x,
    const u16* __restrict__ Bh_g, const u16* __restrict__ Bl_g,
    const float* __restrict__ c2g,
    float* __restrict__ out_cost, float* __restrict__ out_idx)
{
  // 64 KB A-staging region, later overlaid by B double-buffer (2 x 16 KB).
  __shared__ __align__(16) u16 smem[32768];   // 64 KB
  __shared__ float c2l[K];                    //  4 KB
  __shared__ float redV[256];                 //  1 KB
  __shared__ int   redI[256];                 //  1 KB
  u16* Ah = smem;            // [kc4][q4][m128][j8]
  u16* Al = smem + 16384;

  const int tid = threadIdx.x;
  const int wave = tid >> 6, lane = tid & 63;
  const int wr = wave >> 1, wc = wave & 1;    // wave row/col in 2x2
  const int q = lane >> 4, ln = lane & 15;
  const int m0 = blockIdx.x * MT;

  // ---- stage A tile: fp32 -> (hi,lo) f16, tiled layout ----
  #pragma unroll
  for (int i = 0; i < 16; ++i) {
    const int flat = i * 256 + tid;            // 4096 float4s = 128x128 floats
    const int m = flat >> 5, c4 = flat & 31, k0 = c4 * 4;
    const float4 v = *(const float4*)(x + (size_t)(m0 + m) * D + k0);
    const int kc = k0 >> 5, qq = (k0 >> 3) & 3, j0 = k0 & 7;
    const float vv[4] = {v.x, v.y, v.z, v.w};
    H2U h[4], l[4];
    #pragma unroll
    for (int z = 0; z < 4; ++z) {
      h[z].h = (_Float16)vv[z];
      l[z].h = (_Float16)(vv[z] - (float)h[z].h);
    }
    const int off = ((kc * 4 + qq) * 128 + m) * 8 + j0;
    uint2 hp, lp;
    hp.x = h[0].u | ((unsigned)h[1].u << 16); hp.y = h[2].u | ((unsigned)h[3].u << 16);
    lp.x = l[0].u | ((unsigned)l[1].u << 16); lp.y = l[2].u | ((unsigned)l[3].u << 16);
    *(uint2*)(Ah + off) = hp;
    *(uint2*)(Al + off) = lp;
  }
  for (int i = tid; i < K; i += 256) c2l[i] = c2g[i];
  __syncthreads();

  // ---- A panel into registers: [limb][kc][t] = 32 frags = 128 VGPRs ----
  f16x8 Areg[2][4][4];
  #pragma unroll
  for (int kc = 0; kc < 4; ++kc)
    #pragma unroll
    for (int t = 0; t < 4; ++t) {
      const int moff = ((kc * 4 + q) * 128 + wr * 64 + t * 16 + ln) * 8;
      Areg[0][kc][t] = *(const f16x8*)(Ah + moff);
      Areg[1][kc][t] = *(const f16x8*)(Al + moff);
    }

  // ---- x2 per point (thread tid<128 owns m=tid), from LDS before overlay ----
  float x2m = 0.f;
  if (tid < MT) {
    #pragma unroll
    for (int kq = 0; kq < 16; ++kq) {
      const f16x8 hv = *(const f16x8*)(Ah + (kq * 128 + tid) * 8);
      const f16x8 lv = *(const f16x8*)(Al + (kq * 128 + tid) * 8);
      #pragma unroll
      for (int e = 0; e < 8; ++e) {
        const float xv = (float)hv[e] + (float)lv[e];
        x2m += xv * xv;
      }
    }
  }
  __syncthreads();   // A region free -> becomes B double-buffer

  // B double-buffer: buf p at smem + p*8192 (ushorts); Bh [0,4096), Bl [4096,8192)
  auto stageB = [&](int cc, int p) {
    const size_t gbase = (size_t)cc * 4096;   // ushort units per 8 KB limb chunk
    u16* buf = smem + p * 8192;
    #pragma unroll
    for (int i = 0; i < 2; ++i) {
      const size_t eoff = (size_t)i * 2048 + (size_t)wave * 512;  // wave-uniform
      gl_lds16(Bh_g + gbase + eoff + (size_t)lane * 8, buf + eoff);
      gl_lds16(Bl_g + gbase + eoff + (size_t)lane * 8, buf + 4096 + eoff);
    }
  };

  float bestV[16]; int bestI[16];
  #pragma unroll
  for (int b = 0; b < 16; ++b) { bestV[b] = 3.4e38f; bestI[b] = 0; }

  stageB(0, 0);   // prefetch chunk 0

  for (int ct = 0; ct < 8; ++ct) {
    f32x4 acc[4][4];
    #pragma unroll
    for (int mt = 0; mt < 4; ++mt)
      #pragma unroll
      for (int nt = 0; nt < 4; ++nt)
        acc[mt][nt] = (f32x4){0.f, 0.f, 0.f, 0.f};

    #pragma unroll
    for (int kc = 0; kc < 4; ++kc) {
      // chunk cc = ct*4+kc, buffer parity = kc&1 (ct*4 is even)
      __syncthreads();   // own-vmcnt drain -> buf[kc&1] ready; prior reads of
                         // buf[(kc+1)&1] (last iter) ordered before its refill
      if (kc < 3) {
        stageB(ct * 4 + kc + 1, (kc + 1) & 1);
      } else if (ct < 7) {
        stageB(ct * 4 + 4, 0);
      }
      const u16* buf = smem + (kc & 1) * 8192;

      f16x8 bh[4], bl[4];
      #pragma unroll
      for (int t = 0; t < 4; ++t) {
        const int noff = (q * 128 + wc * 64 + t * 16 + ln) * 8;
        bh[t] = *(const f16x8*)(buf + noff);
        bl[t] = *(const f16x8*)(buf + 4096 + noff);
      }
      // 3-pass split-f16: 48 MFMA per chunk, A from registers
      #pragma unroll
      for (int mt = 0; mt < 4; ++mt)
        #pragma unroll
        for (int nt = 0; nt < 4; ++nt)
          acc[mt][nt] = __builtin_amdgcn_mfma_f32_16x16x32_f16(Areg[0][kc][mt], bh[nt], acc[mt][nt], 0, 0, 0);
      #pragma unroll
      for (int mt = 0; mt < 4; ++mt)
        #pragma unroll
        for (int nt = 0; nt < 4; ++nt)
          acc[mt][nt] = __builtin_amdgcn_mfma_f32_16x16x32_f16(Areg[1][kc][mt], bh[nt], acc[mt][nt], 0, 0, 0);
      #pragma unroll
      for (int mt = 0; mt < 4; ++mt)
        #pragma unroll
        for (int nt = 0; nt < 4; ++nt)
          acc[mt][nt] = __builtin_amdgcn_mfma_f32_16x16x32_f16(Areg[0][kc][mt], bl[nt], acc[mt][nt], 0, 0, 0);
    }

    // epilogue: s = c2 - 2*dot; running min (n strictly increasing per lane)
    #pragma unroll
    for (int nt = 0; nt < 4; ++nt) {
      const int n = ct * 128 + wc * 64 + nt * 16 + ln;
      const float c2v = c2l[n];
      #pragma unroll
      for (int mt = 0; mt < 4; ++mt)
        #pragma unroll
        for (int r = 0; r < 4; ++r) {
          const float s = __builtin_fmaf(-2.f, acc[mt][nt][r], c2v);
          const int b = mt * 4 + r;
          if (s < bestV[b]) { bestV[b] = s; bestI[b] = n; }
        }
    }
  }

  // ---- reduce across the 16 lanes (ln) sharing the same m rows ----
  #pragma unroll
  for (int b = 0; b < 16; ++b) {
    float v = bestV[b]; int idx = bestI[b];
    #pragma unroll
    for (int off = 1; off < 16; off <<= 1) {
      const float ov = __shfl_xor(v, off, 64);
      const int   oi = __shfl_xor(idx, off, 64);
      if (ov < v || (ov == v && oi < idx)) { v = ov; idx = oi; }
    }
    bestV[b] = v; bestI[b] = idx;
  }

  if (ln == 0) {
    #pragma unroll
    for (int b = 0; b < 16; ++b) {
      const int ml = wr * 64 + (b >> 2) * 16 + q * 4 + (b & 3);
      redV[ml * 2 + wc] = bestV[b];
      redI[ml * 2 + wc] = bestI[b];
    }
  }
  __syncthreads();
  if (tid < MT) {
    float v = redV[tid * 2]; int idx = redI[tid * 2];
    const float v1 = redV[tid * 2 + 1]; const int i1 = redI[tid * 2 + 1];
    if (v1 < v || (v1 == v && i1 < idx)) { v = v1; idx = i1; }
    float cost = x2m + v;
    if (cost < 0.f) cost = 0.f;          // clamp like reference
    out_cost[m0 + tid] = cost;
    out_idx[m0 + tid]  = (float)idx;
  }
}

extern "C" void kernel_launch(void* const* d_in, const int* in_sizes, int n_in,
                              void* d_out, int out_size, void* d_ws, size_t ws_size,
                              hipStream_t stream) {
  const float* x       = (const float*)d_in[0];
  const float* centers = (const float*)d_in[1];
  u16*   Bh = (u16*)d_ws;                    // 256 KB
  u16*   Bl = Bh + (size_t)K * D;            // 256 KB
  float* c2 = (float*)(Bl + (size_t)K * D);  // 4 KB
  float* out_cost = (float*)d_out;
  float* out_idx  = out_cost + N;

  prep_centers<<<K / 4, 256, 0, stream>>>(centers, Bh, Bl, c2);
  kmeans_mfma<<<N / MT, 256, 0, stream>>>(x, Bh, Bl, c2, out_cost, out_idx);
}

// Round 5
// 179.404 us; speedup vs baseline: 1.7116x; 1.1133x over previous
//
#include <hip/hip_runtime.h>

// KMeans assignment: costs[i] = min_k ||x_i-c_k||^2, indices[i] = argmin_k.
// argmin over k of (c2[k] - 2*dot(x,c_k)); x2 additive, added at the end.
// Cross term via split-f16 3-pass MFMA (xh.ch + xl.ch + xh.cl), err ~1e-6.
// R5: A stays in LDS (no register panel -- R4's spilled). LDS-port diet:
//   - Bh staged via global_load_lds into a 2x8KB double buffer, ONE barrier
//     per chunk, prefetch issued a full chunk-compute ahead (drain ~free).
//   - Bl fragments register-prefetched straight from L2 (16 VGPRs in flight).
//   - c2 read direct from L2 in the epilogue; reduce arrays overlay B buf.
// LDS = 64KB (A) + 16KB (Bh dbuf) = 80KB -> 2 blocks/CU.
// N=131072, D=128, K=1024.  d_out = [costs (N f32), indices-as-f32 (N)].

typedef _Float16 f16x8 __attribute__((ext_vector_type(8)));
typedef float    f32x4 __attribute__((ext_vector_type(4)));
typedef unsigned short u16;

constexpr int N = 131072, D = 128, K = 1024;
constexpr int MT = 128;   // points per block

union H2U { _Float16 h; unsigned short u; };

__device__ inline void gl_lds16(const void* g, void* l) {
  __builtin_amdgcn_global_load_lds(
      (const __attribute__((address_space(1))) unsigned int*)g,
      (__attribute__((address_space(3))) unsigned int*)l, 16, 0, 0);
}

// ---- prep: centers -> hi/lo f16 in fragment-major tiled layout + exact c2 ----
// ushort idx: (((cb*4 + kc)*4 + q)*128 + c%128)*8 + j, k = kc*32 + q*8 + j
__global__ void prep_centers(const float* __restrict__ centers,
                             u16* __restrict__ Bh, u16* __restrict__ Bl,
                             float* __restrict__ c2) {
  const int wave = threadIdx.x >> 6, lane = threadIdx.x & 63;
  const int c = blockIdx.x * 4 + wave;          // one wave per center
  const float2 v = ((const float2*)(centers + (size_t)c * D))[lane];
  float s = v.x * v.x + v.y * v.y;
  #pragma unroll
  for (int off = 32; off; off >>= 1) s += __shfl_xor(s, off, 64);
  if (lane == 0) c2[c] = s;

  H2U h0, h1, l0, l1;
  h0.h = (_Float16)v.x;  l0.h = (_Float16)(v.x - (float)h0.h);
  h1.h = (_Float16)v.y;  l1.h = (_Float16)(v.y - (float)h1.h);
  const int cb = c >> 7, cm = c & 127;
  const int kc = lane >> 4, q = (lane >> 2) & 3, j0 = (lane & 3) * 2;
  const size_t off = (((size_t)(cb * 4 + kc) * 4 + q) * 128 + cm) * 8 + j0;
  *(unsigned*)(Bh + off) = (unsigned)h0.u | ((unsigned)h1.u << 16);
  *(unsigned*)(Bl + off) = (unsigned)l0.u | ((unsigned)l1.u << 16);
}

// ---- main: 128 pts x 1024 centers per block; wave tile 64x64 (2x2 waves) ----
__global__ __launch_bounds__(256, 2) void kmeans_mfma(
    const float* __restrict__ x,
    const u16* __restrict__ Bh_g, const u16* __restrict__ Bl_g,
    const float* __restrict__ c2g,
    float* __restrict__ out_cost, float* __restrict__ out_idx)
{
  // 80 KB total: A [0,32768) u16, Bh dbuf [32768,40960) u16 (2 x 4096)
  __shared__ __align__(16) u16 smem[40960];
  u16* Ah = smem;            // [kc4][q4][m128][j8]  32 KB
  u16* Al = smem + 16384;    //                      32 KB

  const int tid = threadIdx.x;
  const int wave = tid >> 6, lane = tid & 63;
  const int wr = wave >> 1, wc = wave & 1;    // wave row/col in 2x2
  const int q = lane >> 4, ln = lane & 15;
  const int m0 = blockIdx.x * MT;

  // ---- stage A tile: fp32 -> (hi,lo) f16, tiled layout ----
  #pragma unroll
  for (int i = 0; i < 16; ++i) {
    const int flat = i * 256 + tid;            // 4096 float4s = 128x128 floats
    const int m = flat >> 5, c4 = flat & 31, k0 = c4 * 4;
    const float4 v = *(const float4*)(x + (size_t)(m0 + m) * D + k0);
    const int kc = k0 >> 5, qq = (k0 >> 3) & 3, j0 = k0 & 7;
    const float vv[4] = {v.x, v.y, v.z, v.w};
    H2U h[4], l[4];
    #pragma unroll
    for (int z = 0; z < 4; ++z) {
      h[z].h = (_Float16)vv[z];
      l[z].h = (_Float16)(vv[z] - (float)h[z].h);
    }
    const int off = ((kc * 4 + qq) * 128 + m) * 8 + j0;
    uint2 hp, lp;
    hp.x = h[0].u | ((unsigned)h[1].u << 16); hp.y = h[2].u | ((unsigned)h[3].u << 16);
    lp.x = l[0].u | ((unsigned)l[1].u << 16); lp.y = l[2].u | ((unsigned)l[3].u << 16);
    *(uint2*)(Ah + off) = hp;
    *(uint2*)(Al + off) = lp;
  }
  __syncthreads();

  // ---- x2 per point (thread tid<128 owns m=tid); A persists in LDS ----
  float x2m = 0.f;
  if (tid < MT) {
    #pragma unroll
    for (int kq = 0; kq < 16; ++kq) {
      const f16x8 hv = *(const f16x8*)(Ah + (kq * 128 + tid) * 8);
      const f16x8 lv = *(const f16x8*)(Al + (kq * 128 + tid) * 8);
      #pragma unroll
      for (int e = 0; e < 8; ++e) {
        const float xv = (float)hv[e] + (float)lv[e];
        x2m += xv * xv;
      }
    }
  }

  // Bh double-buffer staging (8 KB per chunk)
  auto stageBh = [&](int cc, int p) {
    const size_t gbase = (size_t)cc * 4096;   // u16 per chunk (128c x 32k)
    u16* buf = smem + 32768 + p * 4096;
    #pragma unroll
    for (int i = 0; i < 2; ++i) {
      const size_t eoff = (size_t)i * 2048 + (size_t)wave * 512;  // wave-uniform
      gl_lds16(Bh_g + gbase + eoff + (size_t)lane * 8, buf + eoff);
    }
  };
  // Bl register fragment address (L2-resident, fragment-major)
  auto blPtr = [&](int cc, int t) {
    return (const f16x8*)(Bl_g +
        ((size_t)(cc * 4 + q) * 128 + wc * 64 + t * 16 + ln) * 8);
  };

  float bestV[16]; int bestI[16];
  #pragma unroll
  for (int b = 0; b < 16; ++b) { bestV[b] = 3.4e38f; bestI[b] = 0; }

  stageBh(0, 0);
  f16x8 blc[4], bln[4];
  #pragma unroll
  for (int t = 0; t < 4; ++t) blc[t] = *blPtr(0, t);

  for (int ct = 0; ct < 8; ++ct) {
    f32x4 acc[4][4];
    #pragma unroll
    for (int mt = 0; mt < 4; ++mt)
      #pragma unroll
      for (int nt = 0; nt < 4; ++nt)
        acc[mt][nt] = (f32x4){0.f, 0.f, 0.f, 0.f};

    // c2 for this ct tile, direct from L2; hidden under the 4-chunk compute
    float c2v[4];
    #pragma unroll
    for (int nt = 0; nt < 4; ++nt)
      c2v[nt] = c2g[ct * 128 + wc * 64 + nt * 16 + ln];

    #pragma unroll
    for (int kc = 0; kc < 4; ++kc) {
      const int cc = ct * 4 + kc;              // chunk id, parity = cc&1
      __syncthreads();   // own-vmcnt drained -> buf[cc&1] + blc ready
      if (cc < 31) {
        stageBh(cc + 1, (cc + 1) & 1);         // Bh prefetch, 1 chunk ahead
        #pragma unroll
        for (int t = 0; t < 4; ++t) bln[t] = *blPtr(cc + 1, t);  // Bl prefetch
      }
      const u16* buf = smem + 32768 + (cc & 1) * 4096;

      f16x8 ah[4], al[4], bh[4];
      #pragma unroll
      for (int t = 0; t < 4; ++t) {
        const int moff = ((kc * 4 + q) * 128 + wr * 64 + t * 16 + ln) * 8;
        ah[t] = *(const f16x8*)(Ah + moff);
        al[t] = *(const f16x8*)(Al + moff);
        bh[t] = *(const f16x8*)(buf + (q * 128 + wc * 64 + t * 16 + ln) * 8);
      }
      // 3-pass split-f16: 48 MFMA per chunk
      #pragma unroll
      for (int mt = 0; mt < 4; ++mt)
        #pragma unroll
        for (int nt = 0; nt < 4; ++nt)
          acc[mt][nt] = __builtin_amdgcn_mfma_f32_16x16x32_f16(ah[mt], bh[nt], acc[mt][nt], 0, 0, 0);
      #pragma unroll
      for (int mt = 0; mt < 4; ++mt)
        #pragma unroll
        for (int nt = 0; nt < 4; ++nt)
          acc[mt][nt] = __builtin_amdgcn_mfma_f32_16x16x32_f16(al[mt], bh[nt], acc[mt][nt], 0, 0, 0);
      #pragma unroll
      for (int mt = 0; mt < 4; ++mt)
        #pragma unroll
        for (int nt = 0; nt < 4; ++nt)
          acc[mt][nt] = __builtin_amdgcn_mfma_f32_16x16x32_f16(ah[mt], blc[nt], acc[mt][nt], 0, 0, 0);
      #pragma unroll
      for (int t = 0; t < 4; ++t) blc[t] = bln[t];
    }

    // epilogue: s = c2 - 2*dot; running min (n strictly increasing per lane)
    #pragma unroll
    for (int nt = 0; nt < 4; ++nt) {
      const int n = ct * 128 + wc * 64 + nt * 16 + ln;
      #pragma unroll
      for (int mt = 0; mt < 4; ++mt)
        #pragma unroll
        for (int r = 0; r < 4; ++r) {
          const float s = __builtin_fmaf(-2.f, acc[mt][nt][r], c2v[nt]);
          const int b = mt * 4 + r;
          if (s < bestV[b]) { bestV[b] = s; bestI[b] = n; }
        }
    }
  }

  // ---- reduce across the 16 lanes (ln) sharing the same m rows ----
  #pragma unroll
  for (int b = 0; b < 16; ++b) {
    float v = bestV[b]; int idx = bestI[b];
    #pragma unroll
    for (int off = 1; off < 16; off <<= 1) {
      const float ov = __shfl_xor(v, off, 64);
      const int   oi = __shfl_xor(idx, off, 64);
      if (ov < v || (ov == v && oi < idx)) { v = ov; idx = oi; }
    }
    bestV[b] = v; bestI[b] = idx;
  }

  __syncthreads();                       // all Bh-buf reads done -> overlay
  float* redV = (float*)(smem + 32768);  // 1 KB
  int*   redI = (int*)(smem + 33280);    // 1 KB
  if (ln == 0) {
    #pragma unroll
    for (int b = 0; b < 16; ++b) {
      const int ml = wr * 64 + (b >> 2) * 16 + q * 4 + (b & 3);
      redV[ml * 2 + wc] = bestV[b];
      redI[ml * 2 + wc] = bestI[b];
    }
  }
  __syncthreads();
  if (tid < MT) {
    float v = redV[tid * 2]; int idx = redI[tid * 2];
    const float v1 = redV[tid * 2 + 1]; const int i1 = redI[tid * 2 + 1];
    if (v1 < v || (v1 == v && i1 < idx)) { v = v1; idx = i1; }
    float cost = x2m + v;
    if (cost < 0.f) cost = 0.f;          // clamp like reference
    out_cost[m0 + tid] = cost;
    out_idx[m0 + tid]  = (float)idx;
  }
}

extern "C" void kernel_launch(void* const* d_in, const int* in_sizes, int n_in,
                              void* d_out, int out_size, void* d_ws, size_t ws_size,
                              hipStream_t stream) {
  const float* x       = (const float*)d_in[0];
  const float* centers = (const float*)d_in[1];
  u16*   Bh = (u16*)d_ws;                    // 256 KB
  u16*   Bl = Bh + (size_t)K * D;            // 256 KB
  float* c2 = (float*)(Bl + (size_t)K * D);  // 4 KB
  float* out_cost = (float*)d_out;
  float* out_idx  = out_cost + N;

  prep_centers<<<K / 4, 256, 0, stream>>>(centers, Bh, Bl, c2);
  kmeans_mfma<<<N / MT, 256, 0, stream>>>(x, Bh, Bl, c2, out_cost, out_idx);
}